// Round 1
// baseline (66.010 us; speedup 1.0000x reference)
//
#include <hip/hip_runtime.h>
#include <math.h>

// QuGCN chain-product kernel.
// Key identity: M_i = U rho_i U^dag = v_i v_i^dag (rank-1, v_i = U f_i / ||f_i||),
// so chain = v_0 * (prod_i <v_i, v_{i+1}>) * v_{E-1}^dag.
// Product of E-1 complex scalars is accumulated in log-polar form (double).
// |c_i| <= 1 always, so the float32 reference chain underflows to exactly 0;
// we reproduce that by gating s=0 when sum(log|c|) < -85 (< log FLT_MIN).

#define W_MUL 0.63245553203367586640f  // sqrt(2/5) = he_std * lrmul

struct C { float re, im; };
__device__ __forceinline__ C cmul(C a, C b) {
    return { a.re * b.re - a.im * b.im, a.re * b.im + a.im * b.re };
}
__device__ __forceinline__ C cadd(C a, C b) { return { a.re + b.re, a.im + b.im }; }

// u = Rz(w2) Ry(w1) Rx(w0) with angles w*W_MUL; U = kron(u, u)
__device__ __forceinline__ void build_U(const float* __restrict__ w, C U[4][4]) {
    float h0 = w[0] * W_MUL * 0.5f, h1 = w[1] * W_MUL * 0.5f, h2 = w[2] * W_MUL * 0.5f;
    float c0 = cosf(h0), s0 = sinf(h0);
    float c1 = cosf(h1), s1 = sinf(h1);
    float c2 = cosf(h2), s2 = sinf(h2);
    C rx[2][2] = { { {c0, 0.f}, {0.f, -s0} }, { {0.f, -s0}, {c0, 0.f} } };
    C ry[2][2] = { { {c1, 0.f}, {-s1, 0.f} }, { {s1, 0.f}, {c1, 0.f} } };
    C rz[2][2] = { { {c2, -s2}, {0.f, 0.f} }, { {0.f, 0.f}, {c2, s2} } };
    C t[2][2], u[2][2];
    for (int i = 0; i < 2; i++)
        for (int j = 0; j < 2; j++) {
            C acc = {0.f, 0.f};
            for (int k = 0; k < 2; k++) acc = cadd(acc, cmul(ry[i][k], rx[k][j]));
            t[i][j] = acc;
        }
    for (int i = 0; i < 2; i++)
        for (int j = 0; j < 2; j++) {
            C acc = {0.f, 0.f};
            for (int k = 0; k < 2; k++) acc = cadd(acc, cmul(rz[i][k], t[k][j]));
            u[i][j] = acc;
        }
    // kron(u,u)[2a+c][2b+d] = u[a][b]*u[c][d]
    for (int a = 0; a < 2; a++)
        for (int b = 0; b < 2; b++)
            for (int c = 0; c < 2; c++)
                for (int d = 0; d < 2; d++)
                    U[2 * a + c][2 * b + d] = cmul(u[a][b], u[c][d]);
}

// v = U * [nf[e0], nf[e1]] / ||f||   (unit complex 4-vector)
__device__ __forceinline__ void edge_v(const int* __restrict__ edges,
                                       const float* __restrict__ nf,
                                       int i, const C U[4][4], C v[4]) {
    int a = edges[2 * i], b = edges[2 * i + 1];
    float f0 = nf[2 * a], f1 = nf[2 * a + 1];
    float f2 = nf[2 * b], f3 = nf[2 * b + 1];
    float n2 = f0 * f0 + f1 * f1 + f2 * f2 + f3 * f3;
    float inv = rsqrtf(n2);
    float f[4] = { f0, f1, f2, f3 };
    for (int k = 0; k < 4; k++) {
        float re = 0.f, im = 0.f;
        for (int j = 0; j < 4; j++) {
            re += U[k][j].re * f[j];
            im += U[k][j].im * f[j];
        }
        v[k] = { re * inv, im * inv };
    }
}

// Accumulate sum(log|c_i|) and sum(arg(c_i)) over i in [0, nitems)
__global__ void __launch_bounds__(256)
k_scalars(const int* __restrict__ edges, const float* __restrict__ nf,
          const float* __restrict__ weight, int nitems, double* __restrict__ acc) {
    C U[4][4];
    build_U(weight, U);
    double lsum = 0.0, psum = 0.0;
    for (int i = blockIdx.x * blockDim.x + threadIdx.x; i < nitems;
         i += gridDim.x * blockDim.x) {
        C vi[4], vj[4];
        edge_v(edges, nf, i, U, vi);
        edge_v(edges, nf, i + 1, U, vj);
        float re = 0.f, im = 0.f;
        for (int k = 0; k < 4; k++) {
            re += vi[k].re * vj[k].re + vi[k].im * vj[k].im;  // conj(vi).vj
            im += vi[k].re * vj[k].im - vi[k].im * vj[k].re;
        }
        float m2 = re * re + im * im;
        lsum += 0.5 * (double)logf(m2);     // log(0) = -inf is fine (gated later)
        psum += (double)atan2f(im, re);
    }
    // wave64 butterfly reduce, then cross-wave via LDS, one atomic per block
    for (int off = 32; off; off >>= 1) {
        lsum += __shfl_down(lsum, off, 64);
        psum += __shfl_down(psum, off, 64);
    }
    __shared__ double sl[8], sp[8];
    int wid = threadIdx.x >> 6, lid = threadIdx.x & 63;
    if (lid == 0) { sl[wid] = lsum; sp[wid] = psum; }
    __syncthreads();
    if (threadIdx.x == 0) {
        double L = 0.0, P = 0.0;
        int nw = (blockDim.x + 63) >> 6;
        for (int w = 0; w < nw; w++) { L += sl[w]; P += sp[w]; }
        atomicAdd(&acc[0], L);
        atomicAdd(&acc[1], P);
    }
}

// chain = s * v0 * vl^dag ; x = real(chain) flat[16]; logits = x @ lin_w.T + lin_b; softmax
__global__ void k_final(const int* __restrict__ edges, const float* __restrict__ nf,
                        const float* __restrict__ weight,
                        const float* __restrict__ lin_w, const float* __restrict__ lin_b,
                        int E, const double* __restrict__ acc, float* __restrict__ out) {
    if (threadIdx.x != 0 || blockIdx.x != 0) return;
    C U[4][4];
    build_U(weight, U);
    C v0[4], vl[4];
    edge_v(edges, nf, 0, U, v0);
    edge_v(edges, nf, E - 1, U, vl);
    double L = acc[0], P = acc[1];
    C s;
    if (!(L > -85.0)) {              // covers huge-negative and -inf: float32 chain underflowed
        s = { 0.f, 0.f };
    } else {
        double m = exp(L);
        s = { (float)(m * cos(P)), (float)(m * sin(P)) };
    }
    float x[16];
    for (int a = 0; a < 4; a++)
        for (int d = 0; d < 4; d++) {
            C vld = { vl[d].re, -vl[d].im };           // conj
            C t = cmul(s, cmul(v0[a], vld));
            x[4 * a + d] = t.re;
        }
    float l0 = lin_b[0], l1 = lin_b[1];
    for (int k = 0; k < 16; k++) {
        l0 += x[k] * lin_w[k];        // lin_w row 0
        l1 += x[k] * lin_w[16 + k];   // lin_w row 1
    }
    float mx = fmaxf(l0, l1);
    float e0 = expf(l0 - mx), e1 = expf(l1 - mx);
    float inv = 1.f / (e0 + e1);
    out[0] = e0 * inv;
    out[1] = e1 * inv;
}

extern "C" void kernel_launch(void* const* d_in, const int* in_sizes, int n_in,
                              void* d_out, int out_size, void* d_ws, size_t ws_size,
                              hipStream_t stream) {
    const int*   edges  = (const int*)d_in[0];    // [E,2] (harness delivers int32)
    const float* nf     = (const float*)d_in[1];  // [N,2]
    const float* weight = (const float*)d_in[2];  // [5]
    const float* lin_w  = (const float*)d_in[3];  // [2,16]
    const float* lin_b  = (const float*)d_in[4];  // [2]
    float* out = (float*)d_out;
    double* acc = (double*)d_ws;                  // acc[0]=sum log|c|, acc[1]=sum arg(c)

    int E = in_sizes[0] / 2;
    int nitems = E - 1;

    hipMemsetAsync(d_ws, 0, 2 * sizeof(double), stream);  // zero accumulators every call

    int threads = 256;
    int blocks = (nitems + threads - 1) / threads;
    if (blocks > 2048) blocks = 2048;
    k_scalars<<<blocks, threads, 0, stream>>>(edges, nf, weight, nitems, acc);
    k_final<<<1, 64, 0, stream>>>(edges, nf, weight, lin_w, lin_b, E, acc, out);
}

// Round 2
// 16.488 us; speedup vs baseline: 4.0036x; 4.0036x over previous
//
#include <hip/hip_runtime.h>
#include <math.h>

// QuGCN chain-product kernel, round 2.
// Identity: M_i = U rho_i U^dag = v_i v_i^dag (rank-1, v_i = U f_i / ||f_i||),
// so chain = v_0 * (prod_i <v_i, v_{i+1}>) * v_{E-1}^dag.
// The E-1 complex scalars are reduced in log-polar form (double partials).
// |c_i| <= 1, so the float32 reference chain underflows to exactly 0; we
// reproduce that by gating s=0 when sum(log|c|) < -85 (< log FLT_MIN).
//
// R2 changes vs R1 (57us, 12.8% VALU, 1.2% HBM -> latency/serialization bound):
//  - NO atomics: 4096 same-address f64 atomicAdds (~30cyc each serialized at one
//    L2 bank ~ 51us) replaced by per-block partials in d_ws + reduce kernel.
//  - K=4 items/thread: int4 edge loads, 10 independent up-front gathers (MLP),
//    per-edge v computed once ((K+1)/K redundancy instead of 2x).

#define W_MUL 0.63245553203367586640f  // sqrt(2/5) = he_std * lrmul
#define KITEMS 4

struct C { float re, im; };
__device__ __forceinline__ C cmul(C a, C b) {
    return { a.re * b.re - a.im * b.im, a.re * b.im + a.im * b.re };
}
__device__ __forceinline__ C cadd(C a, C b) { return { a.re + b.re, a.im + b.im }; }

// u = Rz(w2) Ry(w1) Rx(w0) with angles w*W_MUL; U = kron(u, u)
__device__ __forceinline__ void build_U(const float* __restrict__ w, C U[4][4]) {
    float h0 = w[0] * W_MUL * 0.5f, h1 = w[1] * W_MUL * 0.5f, h2 = w[2] * W_MUL * 0.5f;
    float c0 = cosf(h0), s0 = sinf(h0);
    float c1 = cosf(h1), s1 = sinf(h1);
    float c2 = cosf(h2), s2 = sinf(h2);
    C rx[2][2] = { { {c0, 0.f}, {0.f, -s0} }, { {0.f, -s0}, {c0, 0.f} } };
    C ry[2][2] = { { {c1, 0.f}, {-s1, 0.f} }, { {s1, 0.f}, {c1, 0.f} } };
    C rz[2][2] = { { {c2, -s2}, {0.f, 0.f} }, { {0.f, 0.f}, {c2, s2} } };
    C t[2][2], u[2][2];
    for (int i = 0; i < 2; i++)
        for (int j = 0; j < 2; j++) {
            C acc = {0.f, 0.f};
            for (int k = 0; k < 2; k++) acc = cadd(acc, cmul(ry[i][k], rx[k][j]));
            t[i][j] = acc;
        }
    for (int i = 0; i < 2; i++)
        for (int j = 0; j < 2; j++) {
            C acc = {0.f, 0.f};
            for (int k = 0; k < 2; k++) acc = cadd(acc, cmul(rz[i][k], t[k][j]));
            u[i][j] = acc;
        }
    for (int a = 0; a < 2; a++)
        for (int b = 0; b < 2; b++)
            for (int c = 0; c < 2; c++)
                for (int d = 0; d < 2; d++)
                    U[2 * a + c][2 * b + d] = cmul(u[a][b], u[c][d]);
}

// v = U * [fa, fb] / ||f||   from pre-gathered node features
__device__ __forceinline__ void edge_v2(float2 fa, float2 fb, const C U[4][4], C v[4]) {
    float f[4] = { fa.x, fa.y, fb.x, fb.y };
    float n2 = f[0] * f[0] + f[1] * f[1] + f[2] * f[2] + f[3] * f[3];
    float inv = rsqrtf(n2);
    #pragma unroll
    for (int k = 0; k < 4; k++) {
        float re = 0.f, im = 0.f;
        #pragma unroll
        for (int j = 0; j < 4; j++) {
            re += U[k][j].re * f[j];
            im += U[k][j].im * f[j];
        }
        v[k] = { re * inv, im * inv };
    }
}

// Per-thread: KITEMS consecutive items; block partial -> partials[2*blockIdx+{0,1}]
__global__ void __launch_bounds__(256)
k_scalars(const int* __restrict__ edges, const float2* __restrict__ nf,
          const float* __restrict__ weight, int nitems,
          double* __restrict__ partials) {
    int tid = blockIdx.x * blockDim.x + threadIdx.x;
    int base = tid * KITEMS;
    double lsum = 0.0, psum = 0.0;

    if (base < nitems) {
        int cnt = min(KITEMS, nitems - base);
        int ia[KITEMS + 1], ib[KITEMS + 1];
        if (cnt == KITEMS) {
            // 2*base = 8*tid ints -> 32B aligned: two int4 + one int2
            const int4* e4 = (const int4*)(edges + 2 * base);
            int4 p0 = e4[0], p1 = e4[1];
            int2 p2 = *(const int2*)(edges + 2 * base + 8);
            ia[0] = p0.x; ib[0] = p0.y; ia[1] = p0.z; ib[1] = p0.w;
            ia[2] = p1.x; ib[2] = p1.y; ia[3] = p1.z; ib[3] = p1.w;
            ia[4] = p2.x; ib[4] = p2.y;
        } else {
            for (int e = 0; e <= KITEMS; e++) {
                if (e <= cnt) { ia[e] = edges[2 * (base + e)]; ib[e] = edges[2 * (base + e) + 1]; }
                else          { ia[e] = 0; ib[e] = 0; }
            }
        }
        // independent compute to hide the edge-load round trip
        C U[4][4];
        build_U(weight, U);
        // all node gathers issued up-front (10 independent 8B loads)
        float2 ga[KITEMS + 1], gb[KITEMS + 1];
        #pragma unroll
        for (int e = 0; e <= KITEMS; e++) { ga[e] = nf[ia[e]]; gb[e] = nf[ib[e]]; }

        C vp[4];
        edge_v2(ga[0], gb[0], U, vp);
        #pragma unroll
        for (int e = 1; e <= KITEMS; e++) {
            if (e > cnt) break;
            C vc[4];
            edge_v2(ga[e], gb[e], U, vc);
            float re = 0.f, im = 0.f;
            #pragma unroll
            for (int k = 0; k < 4; k++) {
                re += vp[k].re * vc[k].re + vp[k].im * vc[k].im;  // conj(vp).vc
                im += vp[k].re * vc[k].im - vp[k].im * vc[k].re;
            }
            float m2 = re * re + im * im;
            lsum += 0.5 * (double)logf(m2);   // log(0) = -inf ok (gated later)
            psum += (double)atan2f(im, re);
            #pragma unroll
            for (int k = 0; k < 4; k++) vp[k] = vc[k];
        }
    }

    // wave64 butterfly, cross-wave LDS, single write per block (no atomics)
    for (int off = 32; off; off >>= 1) {
        lsum += __shfl_down(lsum, off, 64);
        psum += __shfl_down(psum, off, 64);
    }
    __shared__ double sl[4], sp[4];
    int wid = threadIdx.x >> 6, lid = threadIdx.x & 63;
    if (lid == 0) { sl[wid] = lsum; sp[wid] = psum; }
    __syncthreads();
    if (threadIdx.x == 0) {
        double L = lsum, P = psum;
        for (int w = 1; w < (blockDim.x >> 6); w++) { L += sl[w]; P += sp[w]; }
        partials[2 * blockIdx.x]     = L;
        partials[2 * blockIdx.x + 1] = P;
    }
}

// Reduce block partials; chain = s * v0 * vl^dag; linear + softmax
__global__ void __launch_bounds__(256)
k_final(const int* __restrict__ edges, const float* __restrict__ nf,
        const float* __restrict__ weight,
        const float* __restrict__ lin_w, const float* __restrict__ lin_b,
        int E, const double* __restrict__ partials, int nparts,
        float* __restrict__ out) {
    int t = threadIdx.x;
    double L = 0.0, P = 0.0;
    for (int i = t; i < nparts; i += blockDim.x) {
        L += partials[2 * i];
        P += partials[2 * i + 1];
    }
    for (int off = 32; off; off >>= 1) {
        L += __shfl_down(L, off, 64);
        P += __shfl_down(P, off, 64);
    }
    __shared__ double sl[4], sp[4];
    int wid = t >> 6, lid = t & 63;
    if (lid == 0) { sl[wid] = L; sp[wid] = P; }
    __syncthreads();
    if (t != 0) return;
    for (int w = 1; w < (blockDim.x >> 6); w++) { L += sl[w]; P += sp[w]; }

    C U[4][4];
    build_U(weight, U);
    const float2* nf2 = (const float2*)nf;
    C v0[4], vl[4];
    edge_v2(nf2[edges[0]], nf2[edges[1]], U, v0);
    edge_v2(nf2[edges[2 * (E - 1)]], nf2[edges[2 * (E - 1) + 1]], U, vl);

    C s;
    if (!(L > -85.0)) {   // huge-negative or -inf: float32 chain underflowed to 0
        s = { 0.f, 0.f };
    } else {
        double m = exp(L);
        s = { (float)(m * cos(P)), (float)(m * sin(P)) };
    }
    float x[16];
    for (int a = 0; a < 4; a++)
        for (int d = 0; d < 4; d++) {
            C vld = { vl[d].re, -vl[d].im };  // conj
            C tt = cmul(s, cmul(v0[a], vld));
            x[4 * a + d] = tt.re;
        }
    float l0 = lin_b[0], l1 = lin_b[1];
    for (int k = 0; k < 16; k++) {
        l0 += x[k] * lin_w[k];
        l1 += x[k] * lin_w[16 + k];
    }
    float mx = fmaxf(l0, l1);
    float e0 = expf(l0 - mx), e1 = expf(l1 - mx);
    float inv = 1.f / (e0 + e1);
    out[0] = e0 * inv;
    out[1] = e1 * inv;
}

extern "C" void kernel_launch(void* const* d_in, const int* in_sizes, int n_in,
                              void* d_out, int out_size, void* d_ws, size_t ws_size,
                              hipStream_t stream) {
    const int*   edges  = (const int*)d_in[0];    // [E,2] int32
    const float* nf     = (const float*)d_in[1];  // [N,2]
    const float* weight = (const float*)d_in[2];  // [5]
    const float* lin_w  = (const float*)d_in[3];  // [2,16]
    const float* lin_b  = (const float*)d_in[4];  // [2]
    float* out = (float*)d_out;
    double* partials = (double*)d_ws;             // [nblocks][2] doubles

    int E = in_sizes[0] / 2;
    int nitems = E - 1;

    int threads = 256;
    int per_block = threads * KITEMS;
    int blocks = (nitems + per_block - 1) / per_block;   // 512 for E=524288

    k_scalars<<<blocks, threads, 0, stream>>>(edges, (const float2*)nf, weight,
                                              nitems, partials);
    k_final<<<1, threads, 0, stream>>>(edges, nf, weight, lin_w, lin_b,
                                       E, partials, blocks, out);
}